// Round 9
// baseline (215.779 us; speedup 1.0000x reference)
//
#include <hip/hip_runtime.h>
#include <hip/hip_bf16.h>

#define SEQL 2048
#define DMODEL 1024

typedef short bf16x8 __attribute__((ext_vector_type(8)));
typedef short bf16x4 __attribute__((ext_vector_type(4)));
typedef float f32x4 __attribute__((ext_vector_type(4)));
typedef unsigned short u16;

__device__ __forceinline__ u16 f2bf(float f) {
    union { float f; unsigned u; } v; v.f = f;
    unsigned r = v.u + 0x7FFFu + ((v.u >> 16) & 1u);
    return (u16)(r >> 16);
}

// native 2^x (single v_exp_f32)
__device__ __forceinline__ float fexp2(float x) {
#if __has_builtin(__builtin_amdgcn_exp2f)
    return __builtin_amdgcn_exp2f(x);
#else
    return exp2f(x);
#endif
}

// (1/sqrt(d_model)) * log2(e) : fold expf's log2e multiply into the scale
#define SCALE2 0.04508422f

// async 16B global->LDS copy (global_load_lds_dwordx4)
__device__ __forceinline__ void async16(u16* lds, const u16* g) {
    __builtin_amdgcn_global_load_lds(
        (const __attribute__((address_space(1))) unsigned int*)g,
        (__attribute__((address_space(3))) unsigned int*)lds,
        16, 0, 0);
}

// ============================================================================
// Fragment-ordered layouts (16x16x32 convention). Frag = 64 lanes x 8 elems.
// lane = m + 16*quad, elems j=0..7 where (m = non-k index, k = quad*8+j).
//
// K  image per (n,h,kt64): [st 0..3][f 0..1] frag; key=st*16+m, d=f*32+q*8+j
// Vt image per (n,h,kt64): [t4 0..3][kk 0..1] frag; d=t4*16+m, key=kk*32+q*8+j
// W  image per (cb,kt64):  [cj 0..3][f 0..1] frag; col=cj*16+m, k=f*32+q*8+j
// X  image per (rb128,kt64): [rt 0..7][f 0..1] frag; row=rt*16+m, k=f*32+q*8+j
// ============================================================================

#define TSTR 72

__global__ __launch_bounds__(256) void pack_all(
    const float* __restrict__ kg, const float* __restrict__ wg,
    const float* __restrict__ vg, const int* __restrict__ mg,
    u16* __restrict__ kb, u16* __restrict__ wb, u16* __restrict__ vtb,
    float* __restrict__ maskf)
{
    __shared__ __align__(16) u16 T[64 * TSTR];
    const int b = blockIdx.x, t = threadIdx.x;
    u16 o[8];
    if (b < 2048) {
        const int e0 = (b * 256 + t) * 8;
        const int n = e0 >> 21;
        const int s = (e0 >> 10) & 2047;
        const int dm = e0 & 1023, h = dm >> 6, d0 = dm & 63;
        const float4 x0 = *(const float4*)(kg + e0);
        const float4 x1 = *(const float4*)(kg + e0 + 4);
        o[0]=f2bf(x0.x); o[1]=f2bf(x0.y); o[2]=f2bf(x0.z); o[3]=f2bf(x0.w);
        o[4]=f2bf(x1.x); o[5]=f2bf(x1.y); o[6]=f2bf(x1.z); o[7]=f2bf(x1.w);
        const int kt = s >> 6, st = (s >> 4) & 3, m = s & 15;
        const int f = d0 >> 5, qd = (d0 >> 3) & 3;
        u16* dst = kb + ((size_t)((n * 16 + h) * 32 + kt)) * 4096
                      + (st * 2 + f) * 512 + (m + 16 * qd) * 8;
        *(bf16x8*)dst = *(bf16x8*)o;
    } else if (b < 2560) {
        const int e0 = ((b - 2048) * 256 + t) * 8;
        const int col = e0 >> 10, k0 = e0 & 1023;
        const float4 x0 = *(const float4*)(wg + e0);
        const float4 x1 = *(const float4*)(wg + e0 + 4);
        o[0]=f2bf(x0.x); o[1]=f2bf(x0.y); o[2]=f2bf(x0.z); o[3]=f2bf(x0.w);
        o[4]=f2bf(x1.x); o[5]=f2bf(x1.y); o[6]=f2bf(x1.z); o[7]=f2bf(x1.w);
        const int cb = col >> 6, cj = (col >> 4) & 3, m = col & 15;
        const int kt = k0 >> 6, f = (k0 >> 5) & 1, qd = (k0 >> 3) & 3;
        u16* dst = wb + ((size_t)((cb * 16 + kt) * 8 + cj * 2 + f)) * 512
                      + (m + 16 * qd) * 8;
        *(bf16x8*)dst = *(bf16x8*)o;
    } else if (b < 3584) {
        const int bb = b - 2560;
        const int kt = bb & 31, h = (bb >> 5) & 15, n = bb >> 9;
        {
            const int s = t >> 2, d0 = (t & 3) * 16;
            const float* src = vg + ((size_t)(n * SEQL + kt * 64 + s) * DMODEL) + h * 64 + d0;
            u16 w16[16];
            #pragma unroll
            for (int j = 0; j < 16; ++j) w16[j] = f2bf(src[j]);
            *(bf16x8*)&T[s * TSTR + d0]     = *(bf16x8*)&w16[0];
            *(bf16x8*)&T[s * TSTR + d0 + 8] = *(bf16x8*)&w16[8];
        }
        __syncthreads();
        {
            const int d = t >> 2, k0 = (t & 3) * 16;
            u16 w16[16];
            #pragma unroll
            for (int j = 0; j < 16; ++j) w16[j] = T[(k0 + j) * TSTR + d];
            const int t4 = d >> 4, dr = d & 15;
            u16* base = vtb + ((size_t)((n * 16 + h) * 32 + kt)) * 4096;
            #pragma unroll
            for (int g = 0; g < 2; ++g) {
                const int key0 = k0 + g * 8;
                const int kk = key0 >> 5, qk = (key0 >> 3) & 3;
                *(bf16x8*)(base + (t4 * 2 + kk) * 512 + (dr + 16 * qk) * 8)
                    = *(bf16x8*)&w16[g * 8];
            }
        }
    } else {
        #pragma unroll
        for (int i = 0; i < 16; ++i) {
            const int idx = t * 16 + i;
            maskf[idx] = mg[idx] ? 0.0f : -1.0e5f;
        }
    }
}

// ---------- attention: FROZEN R8 structure + T5 setprio around MFMA ---------
// barrier-free main loop, K/V direct from L2, 4-way kt split, in-LDS combine.
__global__ __launch_bounds__(512, 4) void attn_fused(
    const float* __restrict__ qg, const u16* __restrict__ kb,
    const u16* __restrict__ vtb, const float* __restrict__ maskf,
    u16* __restrict__ xb)
{
    // P [8 waves][2048 u16] = 32 KB ; combine reuses full 40 KB as f32 areas
    __shared__ __align__(16) u16 SM[20480];   // 40 KB

    // bijective XCD swizzle: each XCD owns 4 (h,n) groups x their 32 qblk blocks
    const int b = blockIdx.x;                  // 1024 blocks
    const int xcd = b & 7;
    const int j = b >> 3;                      // 0..127
    const int qblk = j & 31;                   // 32 q-tiles of 64 rows
    const int hn = xcd * 4 + (j >> 5);         // 0..31
    const int h = hn & 15;
    const int n = hn >> 4;

    const int tid = threadIdx.x;
    const int wave = tid >> 6, lane = tid & 63;
    const int rg = wave & 1;                   // 32-row group within 64
    const int s = wave >> 1;                   // kt quarter (8 tiles)
    const int lrow = lane & 15, quad = lane >> 4;
    const int q0 = qblk * 64;

    u16* const P_lds = SM + wave * 2048;       // 4 KB per wave (2 qi x 2 frags)

    const u16* ksrc = kb  + ((size_t)(n * 16 + h)) * 131072 + (size_t)s * 32768;
    const u16* vsrc = vtb + ((size_t)(n * 16 + h)) * 131072 + (size_t)s * 32768;
    const float* mrow = maskf + n * SEQL + s * 512;

    // Q fragments ([q=lane&15][d=quad*8+j]); 2 q-tiles per wave
    bf16x8 qf[2][2];
    #pragma unroll
    for (int qi = 0; qi < 2; ++qi) {
        const float* qp = qg + ((size_t)(n * SEQL + q0 + rg * 32 + qi * 16 + lrow) * DMODEL) + h * 64 + quad * 8;
        #pragma unroll
        for (int f = 0; f < 2; ++f) {
            const float4 a = *(const float4*)(qp + f * 32);
            const float4 c = *(const float4*)(qp + f * 32 + 4);
            u16* dst = (u16*)&qf[qi][f];
            dst[0]=f2bf(a.x); dst[1]=f2bf(a.y); dst[2]=f2bf(a.z); dst[3]=f2bf(a.w);
            dst[4]=f2bf(c.x); dst[5]=f2bf(c.y); dst[6]=f2bf(c.z); dst[7]=f2bf(c.w);
        }
    }

    bf16x8 onesf;
    #pragma unroll
    for (int jj = 0; jj < 8; ++jj) ((u16*)&onesf)[jj] = 0x3F80;

    f32x4 oacc[2][4];
    f32x4 lacc[2];
    #pragma unroll
    for (int qi = 0; qi < 2; ++qi) {
        lacc[qi] = (f32x4){0.f, 0.f, 0.f, 0.f};
        #pragma unroll
        for (int t4 = 0; t4 < 4; ++t4) oacc[qi][t4] = (f32x4){0.f, 0.f, 0.f, 0.f};
    }

    for (int i = 0; i < 8; ++i) {
        // batched global->reg fragment loads (16 independent dwordx4 in flight)
        const u16* kp = ksrc + (size_t)i * 4096 + lane * 8;
        const u16* vp = vsrc + (size_t)i * 4096 + lane * 8;
        bf16x8 kf[8], vf[8];
        #pragma unroll
        for (int f = 0; f < 8; ++f) kf[f] = *(const bf16x8*)(kp + f * 512);
        #pragma unroll
        for (int f = 0; f < 8; ++f) vf[f] = *(const bf16x8*)(vp + f * 512);

        // S^T = K Q^T : C col = q (lane&15), C rows = key (quad*4+r)
        #pragma unroll
        for (int st = 0; st < 4; ++st) {
            const f32x4 mv = *(const f32x4*)&mrow[i * 64 + st * 16 + quad * 4];
            // P-write frag coords for key = st*16 + quad*4 + r
            const int kk = st >> 1;
            const int qk = (st & 1) * 2 + (quad >> 1);
            const int j0 = (quad & 1) * 4;
            #pragma unroll
            for (int qi = 0; qi < 2; ++qi) {
                f32x4 sa = (f32x4){0.f, 0.f, 0.f, 0.f};
                __builtin_amdgcn_s_setprio(1);
                sa = __builtin_amdgcn_mfma_f32_16x16x32_bf16(kf[st * 2 + 0], qf[qi][0], sa, 0, 0, 0);
                sa = __builtin_amdgcn_mfma_f32_16x16x32_bf16(kf[st * 2 + 1], qf[qi][1], sa, 0, 0, 0);
                __builtin_amdgcn_s_setprio(0);
                float e0v = fexp2(fmaf(sa[0], SCALE2, mv[0]));
                float e1v = fexp2(fmaf(sa[1], SCALE2, mv[1]));
                float e2v = fexp2(fmaf(sa[2], SCALE2, mv[2]));
                float e3v = fexp2(fmaf(sa[3], SCALE2, mv[3]));
                __hip_bfloat162 h0 = __float22bfloat162_rn(make_float2(e0v, e1v));
                __hip_bfloat162 h1 = __float22bfloat162_rn(make_float2(e2v, e3v));
                union { unsigned u[2]; bf16x4 v; } pk;
                pk.u[0] = *(unsigned*)&h0;
                pk.u[1] = *(unsigned*)&h1;
                *(bf16x4*)&P_lds[(qi * 2 + kk) * 512 + (lrow + 16 * qk) * 8 + j0] = pk.v;
            }
        }
        asm volatile("s_waitcnt lgkmcnt(0)" ::: "memory");  // wave-local P visible

        #pragma unroll
        for (int qi = 0; qi < 2; ++qi) {
            const bf16x8 pf0 = *(const bf16x8*)&P_lds[(qi * 2 + 0) * 512 + lane * 8];
            const bf16x8 pf1 = *(const bf16x8*)&P_lds[(qi * 2 + 1) * 512 + lane * 8];
            __builtin_amdgcn_s_setprio(1);
            lacc[qi] = __builtin_amdgcn_mfma_f32_16x16x32_bf16(pf0, onesf, lacc[qi], 0, 0, 0);
            lacc[qi] = __builtin_amdgcn_mfma_f32_16x16x32_bf16(pf1, onesf, lacc[qi], 0, 0, 0);
            #pragma unroll
            for (int t4 = 0; t4 < 4; ++t4) {
                oacc[qi][t4] = __builtin_amdgcn_mfma_f32_16x16x32_bf16(pf0, vf[t4 * 2 + 0], oacc[qi][t4], 0, 0, 0);
                oacc[qi][t4] = __builtin_amdgcn_mfma_f32_16x16x32_bf16(pf1, vf[t4 * 2 + 1], oacc[qi][t4], 0, 0, 0);
            }
            __builtin_amdgcn_s_setprio(0);
        }
    }

    // ---- 2-stage in-LDS combine over the 4 kt quarters ----
    __syncthreads();   // everyone done with P regions
    float* const CB = (float*)SM;              // 4 areas x 64 lanes x 40 f32 = 40 KB
    if (s >= 2) {
        float* dst = CB + ((size_t)((wave - 4) * 64 + lane)) * 40;
        #pragma unroll
        for (int qi = 0; qi < 2; ++qi) {
            #pragma unroll
            for (int t4 = 0; t4 < 4; ++t4)
                *(f32x4*)(dst + qi * 16 + t4 * 4) = oacc[qi][t4];
            *(f32x4*)(dst + 32 + qi * 4) = lacc[qi];
        }
    }
    __syncthreads();
    if (s < 2) {
        const float* src = CB + ((size_t)(wave * 64 + lane)) * 40;
        #pragma unroll
        for (int qi = 0; qi < 2; ++qi) {
            #pragma unroll
            for (int t4 = 0; t4 < 4; ++t4)
                oacc[qi][t4] += *(const f32x4*)(src + qi * 16 + t4 * 4);
            lacc[qi] += *(const f32x4*)(src + 32 + qi * 4);
        }
    }
    __syncthreads();
    if (s == 1) {
        float* dst = CB + ((size_t)((wave - 2) * 64 + lane)) * 40;
        #pragma unroll
        for (int qi = 0; qi < 2; ++qi) {
            #pragma unroll
            for (int t4 = 0; t4 < 4; ++t4)
                *(f32x4*)(dst + qi * 16 + t4 * 4) = oacc[qi][t4];
            *(f32x4*)(dst + 32 + qi * 4) = lacc[qi];
        }
    }
    __syncthreads();
    if (s == 0) {
        const float* src = CB + ((size_t)(wave * 64 + lane)) * 40;
        #pragma unroll
        for (int qi = 0; qi < 2; ++qi) {
            #pragma unroll
            for (int t4 = 0; t4 < 4; ++t4)
                oacc[qi][t4] += *(const f32x4*)(src + qi * 16 + t4 * 4);
            lacc[qi] += *(const f32x4*)(src + 32 + qi * 4);
        }
        // normalize + write frag-ordered bf16 X (verified mapping)
        #pragma unroll
        for (int qi = 0; qi < 2; ++qi)
            #pragma unroll
            for (int r = 0; r < 4; ++r) {
                const float rinv = 1.0f / lacc[qi][r];
                const int row = n * SEQL + q0 + rg * 32 + qi * 16 + quad * 4 + r;
                const int rb = row >> 7, rt = (row >> 4) & 7, m = row & 15;
                #pragma unroll
                for (int t4 = 0; t4 < 4; ++t4) {
                    const int f = t4 >> 1;
                    const int qd = (t4 & 1) * 2 + (lrow >> 3);
                    xb[((size_t)((rb * 16 + h) * 16 + rt * 2 + f)) * 512
                       + (m + 16 * qd) * 8 + (lrow & 7)] = f2bf(oacc[qi][t4][r] * rinv);
                }
            }
    }
}

// ---------- FC: out = X @ W^T + b, 64x64 tile, BK=64, frag-ordered ----------
// Retiled for occupancy: 1024 blocks (4/CU) x 4 waves, 32 KB LDS dbuf
// -> 16 waves/CU (was 8 at the 128x64 tile / 512-block grid).
__global__ __launch_bounds__(256) void fc_kernel(
    const u16* __restrict__ xb, const u16* __restrict__ wb,
    const float* __restrict__ bias, float* __restrict__ out)
{
    // X dbuf 2x4096 | W dbuf 2x4096 (32 KB)
    __shared__ __align__(16) u16 SM[16384];
    u16* const X_lds = SM;            // [2][4096]
    u16* const W_lds = SM + 8192;     // [2][4096]

    const int blk = blockIdx.x;          // 64 rowblocks x 16 colblocks = 1024
    const int cb = blk & 15, rb = blk >> 4;
    const int tid = threadIdx.x;
    const int wave = tid >> 6, lane = tid & 63;
    const int lrow = lane & 15, quad = lane >> 4;

    // X half-tile (64 rows) is contiguous: frags rt*2+f, rt=(rb&1)*4+wave_local
    const u16* xs0 = xb + ((size_t)(rb >> 1) * 256 + (size_t)(rb & 1) * 8) * 512;
    const u16* ws0 = wb + ((size_t)cb) * 65536;

    f32x4 acc[4];
    #pragma unroll
    for (int cj = 0; cj < 4; ++cj) acc[cj] = (f32x4){0.f, 0.f, 0.f, 0.f};

    // prologue: stage kt=0 into buffer 0 (8 KB X + 8 KB W = 1024 chunks)
    {
        #pragma unroll
        for (int i = 0; i < 2; ++i) {
            const int ch = tid + i * 256;          // 512 chunks each
            async16(&X_lds[ch * 8], xs0 + ch * 8);
            async16(&W_lds[ch * 8], ws0 + ch * 8);
        }
    }
    __syncthreads();

    for (int kt = 0; kt < 16; ++kt) {
        const int cur = kt & 1;
        const u16* const Xc = X_lds + cur * 4096;
        const u16* const Wc = W_lds + cur * 4096;

        if (kt + 1 < 16) {
            const int nxt = cur ^ 1;
            const u16* xs = xs0 + (size_t)(kt + 1) * 8192;
            const u16* ws = ws0 + (size_t)(kt + 1) * 4096;
            #pragma unroll
            for (int i = 0; i < 2; ++i) {
                const int ch = tid + i * 256;
                async16(&X_lds[nxt * 4096 + ch * 8], xs + ch * 8);
                async16(&W_lds[nxt * 4096 + ch * 8], ws + ch * 8);
            }
        }

        const bf16x8 af0 = *(const bf16x8*)&Xc[(wave * 2 + 0) * 512 + lane * 8];
        const bf16x8 af1 = *(const bf16x8*)&Xc[(wave * 2 + 1) * 512 + lane * 8];
        #pragma unroll
        for (int cj = 0; cj < 4; ++cj) {
            const bf16x8 bf0 = *(const bf16x8*)&Wc[(cj * 2 + 0) * 512 + lane * 8];
            const bf16x8 bf1 = *(const bf16x8*)&Wc[(cj * 2 + 1) * 512 + lane * 8];
            acc[cj] = __builtin_amdgcn_mfma_f32_16x16x32_bf16(af0, bf0, acc[cj], 0, 0, 0);
            acc[cj] = __builtin_amdgcn_mfma_f32_16x16x32_bf16(af1, bf1, acc[cj], 0, 0, 0);
        }

        __syncthreads();   // drains vmcnt(0) — next tile landed during compute
    }

    const int row0 = rb * 64 + wave * 16, col0 = cb * 64;
    #pragma unroll
    for (int cj = 0; cj < 4; ++cj) {
        const int col = col0 + cj * 16 + lrow;
        const float bv = bias[col];
        #pragma unroll
        for (int r = 0; r < 4; ++r)
            out[(size_t)(row0 + quad * 4 + r) * DMODEL + col] = acc[cj][r] + bv;
    }
}

extern "C" void kernel_launch(void* const* d_in, const int* in_sizes, int n_in,
                              void* d_out, int out_size, void* d_ws, size_t ws_size,
                              hipStream_t stream) {
    const float* q   = (const float*)d_in[0];
    const float* k   = (const float*)d_in[1];
    const float* v   = (const float*)d_in[2];
    const int*   m   = (const int*)d_in[3];
    const float* fcw = (const float*)d_in[4];
    const float* fcb = (const float*)d_in[5];
    float* out = (float*)d_out;

    char* ws = (char*)d_ws;
    u16*   kbuf  = (u16*)(ws);                     // 8 MB  frag-ordered K
    u16*   vtbuf = (u16*)(ws + (8u  << 20));       // 8 MB  frag-ordered V^T
    u16*   wbuf  = (u16*)(ws + (16u << 20));       // 2 MB  frag-ordered W
    u16*   xbuf  = (u16*)(ws + (18u << 20));       // 8 MB  frag-ordered X
    float* maskf = (float*)(ws + (26u << 20));     // 16 KB float bias [2][2048]

    pack_all<<<dim3(3585), dim3(256), 0, stream>>>(k, fcw, v, m, kbuf, wbuf, vtbuf, maskf);
    attn_fused<<<dim3(1024), dim3(512), 0, stream>>>(q, kbuf, vtbuf, maskf, xbuf);
    fc_kernel<<<dim3(1024), dim3(256), 0, stream>>>(xbuf, wbuf, fcb, out);
}

// Round 10
// 180.784 us; speedup vs baseline: 1.1936x; 1.1936x over previous
//
#include <hip/hip_runtime.h>
#include <hip/hip_bf16.h>

#define SEQL 2048
#define DMODEL 1024

typedef short bf16x8 __attribute__((ext_vector_type(8)));
typedef short bf16x4 __attribute__((ext_vector_type(4)));
typedef float f32x4 __attribute__((ext_vector_type(4)));
typedef unsigned short u16;

__device__ __forceinline__ u16 f2bf(float f) {
    union { float f; unsigned u; } v; v.f = f;
    unsigned r = v.u + 0x7FFFu + ((v.u >> 16) & 1u);
    return (u16)(r >> 16);
}

// native 2^x (single v_exp_f32)
__device__ __forceinline__ float fexp2(float x) {
#if __has_builtin(__builtin_amdgcn_exp2f)
    return __builtin_amdgcn_exp2f(x);
#else
    return exp2f(x);
#endif
}

// (1/sqrt(d_model)) * log2(e) : fold expf's log2e multiply into the scale
#define SCALE2 0.04508422f

// async 16B global->LDS copy (global_load_lds_dwordx4)
__device__ __forceinline__ void async16(u16* lds, const u16* g) {
    __builtin_amdgcn_global_load_lds(
        (const __attribute__((address_space(1))) unsigned int*)g,
        (__attribute__((address_space(3))) unsigned int*)lds,
        16, 0, 0);
}

// ============================================================================
// Fragment-ordered layouts (16x16x32 convention). Frag = 64 lanes x 8 elems.
// lane = m + 16*quad, elems j=0..7 where (m = non-k index, k = quad*8+j).
//
// K  image per (n,h,kt64): [st 0..3][f 0..1] frag; key=st*16+m, d=f*32+q*8+j
// Vt image per (n,h,kt64): [t4 0..3][kk 0..1] frag; d=t4*16+m, key=kk*32+q*8+j
// W  image per (cb,kt64):  [cj 0..3][f 0..1] frag; col=cj*16+m, k=f*32+q*8+j
// X  image per (rb128,kt64): [rt 0..7][f 0..1] frag; row=rt*16+m, k=f*32+q*8+j
// ============================================================================

#define TSTR 72

__global__ __launch_bounds__(256) void pack_all(
    const float* __restrict__ kg, const float* __restrict__ wg,
    const float* __restrict__ vg, const int* __restrict__ mg,
    u16* __restrict__ kb, u16* __restrict__ wb, u16* __restrict__ vtb,
    float* __restrict__ maskf)
{
    __shared__ __align__(16) u16 T[64 * TSTR];
    const int b = blockIdx.x, t = threadIdx.x;
    u16 o[8];
    if (b < 2048) {
        const int e0 = (b * 256 + t) * 8;
        const int n = e0 >> 21;
        const int s = (e0 >> 10) & 2047;
        const int dm = e0 & 1023, h = dm >> 6, d0 = dm & 63;
        const float4 x0 = *(const float4*)(kg + e0);
        const float4 x1 = *(const float4*)(kg + e0 + 4);
        o[0]=f2bf(x0.x); o[1]=f2bf(x0.y); o[2]=f2bf(x0.z); o[3]=f2bf(x0.w);
        o[4]=f2bf(x1.x); o[5]=f2bf(x1.y); o[6]=f2bf(x1.z); o[7]=f2bf(x1.w);
        const int kt = s >> 6, st = (s >> 4) & 3, m = s & 15;
        const int f = d0 >> 5, qd = (d0 >> 3) & 3;
        u16* dst = kb + ((size_t)((n * 16 + h) * 32 + kt)) * 4096
                      + (st * 2 + f) * 512 + (m + 16 * qd) * 8;
        *(bf16x8*)dst = *(bf16x8*)o;
    } else if (b < 2560) {
        const int e0 = ((b - 2048) * 256 + t) * 8;
        const int col = e0 >> 10, k0 = e0 & 1023;
        const float4 x0 = *(const float4*)(wg + e0);
        const float4 x1 = *(const float4*)(wg + e0 + 4);
        o[0]=f2bf(x0.x); o[1]=f2bf(x0.y); o[2]=f2bf(x0.z); o[3]=f2bf(x0.w);
        o[4]=f2bf(x1.x); o[5]=f2bf(x1.y); o[6]=f2bf(x1.z); o[7]=f2bf(x1.w);
        const int cb = col >> 6, cj = (col >> 4) & 3, m = col & 15;
        const int kt = k0 >> 6, f = (k0 >> 5) & 1, qd = (k0 >> 3) & 3;
        u16* dst = wb + ((size_t)((cb * 16 + kt) * 8 + cj * 2 + f)) * 512
                      + (m + 16 * qd) * 8;
        *(bf16x8*)dst = *(bf16x8*)o;
    } else if (b < 3584) {
        const int bb = b - 2560;
        const int kt = bb & 31, h = (bb >> 5) & 15, n = bb >> 9;
        {
            const int s = t >> 2, d0 = (t & 3) * 16;
            const float* src = vg + ((size_t)(n * SEQL + kt * 64 + s) * DMODEL) + h * 64 + d0;
            u16 w16[16];
            #pragma unroll
            for (int j = 0; j < 16; ++j) w16[j] = f2bf(src[j]);
            *(bf16x8*)&T[s * TSTR + d0]     = *(bf16x8*)&w16[0];
            *(bf16x8*)&T[s * TSTR + d0 + 8] = *(bf16x8*)&w16[8];
        }
        __syncthreads();
        {
            const int d = t >> 2, k0 = (t & 3) * 16;
            u16 w16[16];
            #pragma unroll
            for (int j = 0; j < 16; ++j) w16[j] = T[(k0 + j) * TSTR + d];
            const int t4 = d >> 4, dr = d & 15;
            u16* base = vtb + ((size_t)((n * 16 + h) * 32 + kt)) * 4096;
            #pragma unroll
            for (int g = 0; g < 2; ++g) {
                const int key0 = k0 + g * 8;
                const int kk = key0 >> 5, qk = (key0 >> 3) & 3;
                *(bf16x8*)(base + (t4 * 2 + kk) * 512 + (dr + 16 * qk) * 8)
                    = *(bf16x8*)&w16[g * 8];
            }
        }
    } else {
        #pragma unroll
        for (int i = 0; i < 16; ++i) {
            const int idx = t * 16 + i;
            maskf[idx] = mg[idx] ? 0.0f : -1.0e5f;
        }
    }
}

// ---------- attention: EXACT R8 structure (60 VGPR fixed point, no setprio) --
// barrier-free main loop, K/V direct from L2, 4-way kt split, in-LDS combine.
__global__ __launch_bounds__(512, 4) void attn_fused(
    const float* __restrict__ qg, const u16* __restrict__ kb,
    const u16* __restrict__ vtb, const float* __restrict__ maskf,
    u16* __restrict__ xb)
{
    // P [8 waves][2048 u16] = 32 KB ; combine reuses full 40 KB as f32 areas
    __shared__ __align__(16) u16 SM[20480];   // 40 KB

    // bijective XCD swizzle: each XCD owns 4 (h,n) groups x their 32 qblk blocks
    const int b = blockIdx.x;                  // 1024 blocks
    const int xcd = b & 7;
    const int j = b >> 3;                      // 0..127
    const int qblk = j & 31;                   // 32 q-tiles of 64 rows
    const int hn = xcd * 4 + (j >> 5);         // 0..31
    const int h = hn & 15;
    const int n = hn >> 4;

    const int tid = threadIdx.x;
    const int wave = tid >> 6, lane = tid & 63;
    const int rg = wave & 1;                   // 32-row group within 64
    const int s = wave >> 1;                   // kt quarter (8 tiles)
    const int lrow = lane & 15, quad = lane >> 4;
    const int q0 = qblk * 64;

    u16* const P_lds = SM + wave * 2048;       // 4 KB per wave (2 qi x 2 frags)

    const u16* ksrc = kb  + ((size_t)(n * 16 + h)) * 131072 + (size_t)s * 32768;
    const u16* vsrc = vtb + ((size_t)(n * 16 + h)) * 131072 + (size_t)s * 32768;
    const float* mrow = maskf + n * SEQL + s * 512;

    // Q fragments ([q=lane&15][d=quad*8+j]); 2 q-tiles per wave
    bf16x8 qf[2][2];
    #pragma unroll
    for (int qi = 0; qi < 2; ++qi) {
        const float* qp = qg + ((size_t)(n * SEQL + q0 + rg * 32 + qi * 16 + lrow) * DMODEL) + h * 64 + quad * 8;
        #pragma unroll
        for (int f = 0; f < 2; ++f) {
            const float4 a = *(const float4*)(qp + f * 32);
            const float4 c = *(const float4*)(qp + f * 32 + 4);
            u16* dst = (u16*)&qf[qi][f];
            dst[0]=f2bf(a.x); dst[1]=f2bf(a.y); dst[2]=f2bf(a.z); dst[3]=f2bf(a.w);
            dst[4]=f2bf(c.x); dst[5]=f2bf(c.y); dst[6]=f2bf(c.z); dst[7]=f2bf(c.w);
        }
    }

    bf16x8 onesf;
    #pragma unroll
    for (int jj = 0; jj < 8; ++jj) ((u16*)&onesf)[jj] = 0x3F80;

    f32x4 oacc[2][4];
    f32x4 lacc[2];
    #pragma unroll
    for (int qi = 0; qi < 2; ++qi) {
        lacc[qi] = (f32x4){0.f, 0.f, 0.f, 0.f};
        #pragma unroll
        for (int t4 = 0; t4 < 4; ++t4) oacc[qi][t4] = (f32x4){0.f, 0.f, 0.f, 0.f};
    }

    for (int i = 0; i < 8; ++i) {
        // batched global->reg fragment loads (16 independent dwordx4 in flight)
        const u16* kp = ksrc + (size_t)i * 4096 + lane * 8;
        const u16* vp = vsrc + (size_t)i * 4096 + lane * 8;
        bf16x8 kf[8], vf[8];
        #pragma unroll
        for (int f = 0; f < 8; ++f) kf[f] = *(const bf16x8*)(kp + f * 512);
        #pragma unroll
        for (int f = 0; f < 8; ++f) vf[f] = *(const bf16x8*)(vp + f * 512);

        // S^T = K Q^T : C col = q (lane&15), C rows = key (quad*4+r)
        #pragma unroll
        for (int st = 0; st < 4; ++st) {
            const f32x4 mv = *(const f32x4*)&mrow[i * 64 + st * 16 + quad * 4];
            // P-write frag coords for key = st*16 + quad*4 + r
            const int kk = st >> 1;
            const int qk = (st & 1) * 2 + (quad >> 1);
            const int j0 = (quad & 1) * 4;
            #pragma unroll
            for (int qi = 0; qi < 2; ++qi) {
                f32x4 sa = (f32x4){0.f, 0.f, 0.f, 0.f};
                sa = __builtin_amdgcn_mfma_f32_16x16x32_bf16(kf[st * 2 + 0], qf[qi][0], sa, 0, 0, 0);
                sa = __builtin_amdgcn_mfma_f32_16x16x32_bf16(kf[st * 2 + 1], qf[qi][1], sa, 0, 0, 0);
                float e0v = fexp2(fmaf(sa[0], SCALE2, mv[0]));
                float e1v = fexp2(fmaf(sa[1], SCALE2, mv[1]));
                float e2v = fexp2(fmaf(sa[2], SCALE2, mv[2]));
                float e3v = fexp2(fmaf(sa[3], SCALE2, mv[3]));
                __hip_bfloat162 h0 = __float22bfloat162_rn(make_float2(e0v, e1v));
                __hip_bfloat162 h1 = __float22bfloat162_rn(make_float2(e2v, e3v));
                union { unsigned u[2]; bf16x4 v; } pk;
                pk.u[0] = *(unsigned*)&h0;
                pk.u[1] = *(unsigned*)&h1;
                *(bf16x4*)&P_lds[(qi * 2 + kk) * 512 + (lrow + 16 * qk) * 8 + j0] = pk.v;
            }
        }
        asm volatile("s_waitcnt lgkmcnt(0)" ::: "memory");  // wave-local P visible

        #pragma unroll
        for (int qi = 0; qi < 2; ++qi) {
            const bf16x8 pf0 = *(const bf16x8*)&P_lds[(qi * 2 + 0) * 512 + lane * 8];
            const bf16x8 pf1 = *(const bf16x8*)&P_lds[(qi * 2 + 1) * 512 + lane * 8];
            lacc[qi] = __builtin_amdgcn_mfma_f32_16x16x32_bf16(pf0, onesf, lacc[qi], 0, 0, 0);
            lacc[qi] = __builtin_amdgcn_mfma_f32_16x16x32_bf16(pf1, onesf, lacc[qi], 0, 0, 0);
            #pragma unroll
            for (int t4 = 0; t4 < 4; ++t4) {
                oacc[qi][t4] = __builtin_amdgcn_mfma_f32_16x16x32_bf16(pf0, vf[t4 * 2 + 0], oacc[qi][t4], 0, 0, 0);
                oacc[qi][t4] = __builtin_amdgcn_mfma_f32_16x16x32_bf16(pf1, vf[t4 * 2 + 1], oacc[qi][t4], 0, 0, 0);
            }
        }
    }

    // ---- 2-stage in-LDS combine over the 4 kt quarters ----
    __syncthreads();   // everyone done with P regions
    float* const CB = (float*)SM;              // 4 areas x 64 lanes x 40 f32 = 40 KB
    if (s >= 2) {
        float* dst = CB + ((size_t)((wave - 4) * 64 + lane)) * 40;
        #pragma unroll
        for (int qi = 0; qi < 2; ++qi) {
            #pragma unroll
            for (int t4 = 0; t4 < 4; ++t4)
                *(f32x4*)(dst + qi * 16 + t4 * 4) = oacc[qi][t4];
            *(f32x4*)(dst + 32 + qi * 4) = lacc[qi];
        }
    }
    __syncthreads();
    if (s < 2) {
        const float* src = CB + ((size_t)(wave * 64 + lane)) * 40;
        #pragma unroll
        for (int qi = 0; qi < 2; ++qi) {
            #pragma unroll
            for (int t4 = 0; t4 < 4; ++t4)
                oacc[qi][t4] += *(const f32x4*)(src + qi * 16 + t4 * 4);
            lacc[qi] += *(const f32x4*)(src + 32 + qi * 4);
        }
    }
    __syncthreads();
    if (s == 1) {
        float* dst = CB + ((size_t)((wave - 2) * 64 + lane)) * 40;
        #pragma unroll
        for (int qi = 0; qi < 2; ++qi) {
            #pragma unroll
            for (int t4 = 0; t4 < 4; ++t4)
                *(f32x4*)(dst + qi * 16 + t4 * 4) = oacc[qi][t4];
            *(f32x4*)(dst + 32 + qi * 4) = lacc[qi];
        }
    }
    __syncthreads();
    if (s == 0) {
        const float* src = CB + ((size_t)(wave * 64 + lane)) * 40;
        #pragma unroll
        for (int qi = 0; qi < 2; ++qi) {
            #pragma unroll
            for (int t4 = 0; t4 < 4; ++t4)
                oacc[qi][t4] += *(const f32x4*)(src + qi * 16 + t4 * 4);
            lacc[qi] += *(const f32x4*)(src + 32 + qi * 4);
        }
        // normalize + write frag-ordered bf16 X (verified mapping)
        #pragma unroll
        for (int qi = 0; qi < 2; ++qi)
            #pragma unroll
            for (int r = 0; r < 4; ++r) {
                const float rinv = 1.0f / lacc[qi][r];
                const int row = n * SEQL + q0 + rg * 32 + qi * 16 + quad * 4 + r;
                const int rb = row >> 7, rt = (row >> 4) & 7, m = row & 15;
                #pragma unroll
                for (int t4 = 0; t4 < 4; ++t4) {
                    const int f = t4 >> 1;
                    const int qd = (t4 & 1) * 2 + (lrow >> 3);
                    xb[((size_t)((rb * 16 + h) * 16 + rt * 2 + f)) * 512
                       + (m + 16 * qd) * 8 + (lrow & 7)] = f2bf(oacc[qi][t4][r] * rinv);
                }
            }
    }
}

// ---------- FC: out = X @ W^T + b, 64x64 tile, BK=64, frag-ordered ----------
// Retiled for occupancy (R9, kept): 1024 blocks (4/CU) x 4 waves, 32 KB LDS.
__global__ __launch_bounds__(256) void fc_kernel(
    const u16* __restrict__ xb, const u16* __restrict__ wb,
    const float* __restrict__ bias, float* __restrict__ out)
{
    // X dbuf 2x4096 | W dbuf 2x4096 (32 KB)
    __shared__ __align__(16) u16 SM[16384];
    u16* const X_lds = SM;            // [2][4096]
    u16* const W_lds = SM + 8192;     // [2][4096]

    const int blk = blockIdx.x;          // 64 rowblocks x 16 colblocks = 1024
    const int cb = blk & 15, rb = blk >> 4;
    const int tid = threadIdx.x;
    const int wave = tid >> 6, lane = tid & 63;
    const int lrow = lane & 15, quad = lane >> 4;

    // X half-tile (64 rows) is contiguous: frags rt*2+f, rt=(rb&1)*4+wave_local
    const u16* xs0 = xb + ((size_t)(rb >> 1) * 256 + (size_t)(rb & 1) * 8) * 512;
    const u16* ws0 = wb + ((size_t)cb) * 65536;

    f32x4 acc[4];
    #pragma unroll
    for (int cj = 0; cj < 4; ++cj) acc[cj] = (f32x4){0.f, 0.f, 0.f, 0.f};

    // prologue: stage kt=0 into buffer 0 (8 KB X + 8 KB W = 1024 chunks)
    {
        #pragma unroll
        for (int i = 0; i < 2; ++i) {
            const int ch = tid + i * 256;          // 512 chunks each
            async16(&X_lds[ch * 8], xs0 + ch * 8);
            async16(&W_lds[ch * 8], ws0 + ch * 8);
        }
    }
    __syncthreads();

    for (int kt = 0; kt < 16; ++kt) {
        const int cur = kt & 1;
        const u16* const Xc = X_lds + cur * 4096;
        const u16* const Wc = W_lds + cur * 4096;

        if (kt + 1 < 16) {
            const int nxt = cur ^ 1;
            const u16* xs = xs0 + (size_t)(kt + 1) * 8192;
            const u16* ws = ws0 + (size_t)(kt + 1) * 4096;
            #pragma unroll
            for (int i = 0; i < 2; ++i) {
                const int ch = tid + i * 256;
                async16(&X_lds[nxt * 4096 + ch * 8], xs + ch * 8);
                async16(&W_lds[nxt * 4096 + ch * 8], ws + ch * 8);
            }
        }

        const bf16x8 af0 = *(const bf16x8*)&Xc[(wave * 2 + 0) * 512 + lane * 8];
        const bf16x8 af1 = *(const bf16x8*)&Xc[(wave * 2 + 1) * 512 + lane * 8];
        #pragma unroll
        for (int cj = 0; cj < 4; ++cj) {
            const bf16x8 bf0 = *(const bf16x8*)&Wc[(cj * 2 + 0) * 512 + lane * 8];
            const bf16x8 bf1 = *(const bf16x8*)&Wc[(cj * 2 + 1) * 512 + lane * 8];
            acc[cj] = __builtin_amdgcn_mfma_f32_16x16x32_bf16(af0, bf0, acc[cj], 0, 0, 0);
            acc[cj] = __builtin_amdgcn_mfma_f32_16x16x32_bf16(af1, bf1, acc[cj], 0, 0, 0);
        }

        __syncthreads();   // drains vmcnt(0) — next tile landed during compute
    }

    const int row0 = rb * 64 + wave * 16, col0 = cb * 64;
    #pragma unroll
    for (int cj = 0; cj < 4; ++cj) {
        const int col = col0 + cj * 16 + lrow;
        const float bv = bias[col];
        #pragma unroll
        for (int r = 0; r < 4; ++r)
            out[(size_t)(row0 + quad * 4 + r) * DMODEL + col] = acc[cj][r] + bv;
    }
}

extern "C" void kernel_launch(void* const* d_in, const int* in_sizes, int n_in,
                              void* d_out, int out_size, void* d_ws, size_t ws_size,
                              hipStream_t stream) {
    const float* q   = (const float*)d_in[0];
    const float* k   = (const float*)d_in[1];
    const float* v   = (const float*)d_in[2];
    const int*   m   = (const int*)d_in[3];
    const float* fcw = (const float*)d_in[4];
    const float* fcb = (const float*)d_in[5];
    float* out = (float*)d_out;

    char* ws = (char*)d_ws;
    u16*   kbuf  = (u16*)(ws);                     // 8 MB  frag-ordered K
    u16*   vtbuf = (u16*)(ws + (8u  << 20));       // 8 MB  frag-ordered V^T
    u16*   wbuf  = (u16*)(ws + (16u << 20));       // 2 MB  frag-ordered W
    u16*   xbuf  = (u16*)(ws + (18u << 20));       // 8 MB  frag-ordered X
    float* maskf = (float*)(ws + (26u << 20));     // 16 KB float bias [2][2048]

    pack_all<<<dim3(3585), dim3(256), 0, stream>>>(k, fcw, v, m, kbuf, wbuf, vtbuf, maskf);
    attn_fused<<<dim3(1024), dim3(512), 0, stream>>>(q, kbuf, vtbuf, maskf, xbuf);
    fc_kernel<<<dim3(1024), dim3(256), 0, stream>>>(xbuf, wbuf, fcb, out);
}

// Round 11
// 171.588 us; speedup vs baseline: 1.2575x; 1.0536x over previous
//
#include <hip/hip_runtime.h>
#include <hip/hip_bf16.h>

#define SEQL 2048
#define DMODEL 1024

typedef short bf16x8 __attribute__((ext_vector_type(8)));
typedef short bf16x4 __attribute__((ext_vector_type(4)));
typedef float f32x4 __attribute__((ext_vector_type(4)));
typedef unsigned short u16;

__device__ __forceinline__ u16 f2bf(float f) {
    union { float f; unsigned u; } v; v.f = f;
    unsigned r = v.u + 0x7FFFu + ((v.u >> 16) & 1u);
    return (u16)(r >> 16);
}

// native 2^x (single v_exp_f32)
__device__ __forceinline__ float fexp2(float x) {
#if __has_builtin(__builtin_amdgcn_exp2f)
    return __builtin_amdgcn_exp2f(x);
#else
    return exp2f(x);
#endif
}

// (1/sqrt(d_model)) * log2(e) : fold expf's log2e multiply into the scale
#define SCALE2 0.04508422f

// async 16B global->LDS copy (global_load_lds_dwordx4)
__device__ __forceinline__ void async16(u16* lds, const u16* g) {
    __builtin_amdgcn_global_load_lds(
        (const __attribute__((address_space(1))) unsigned int*)g,
        (__attribute__((address_space(3))) unsigned int*)lds,
        16, 0, 0);
}

// ============================================================================
// Fragment-ordered layouts (16x16x32 convention). Frag = 64 lanes x 8 elems.
// lane = m + 16*quad, elems j=0..7 where (m = non-k index, k = quad*8+j).
//
// K  image per (n,h,kt64): [st 0..3][f 0..1] frag; key=st*16+m, d=f*32+q*8+j
// Vt image per (n,h,kt64): [t4 0..3][kk 0..1] frag; d=t4*16+m, key=kk*32+q*8+j
// W  image per (cb,kt64):  [cj 0..3][f 0..1] frag; col=cj*16+m, k=f*32+q*8+j
// X  image per (rb128,kt64): [rt 0..7][f 0..1] frag; row=rt*16+m, k=f*32+q*8+j
// ============================================================================

#define TSTR 72

__global__ __launch_bounds__(256) void pack_all(
    const float* __restrict__ kg, const float* __restrict__ wg,
    const float* __restrict__ vg, const int* __restrict__ mg,
    u16* __restrict__ kb, u16* __restrict__ wb, u16* __restrict__ vtb,
    float* __restrict__ maskf)
{
    __shared__ __align__(16) u16 T[64 * TSTR];
    const int b = blockIdx.x, t = threadIdx.x;
    u16 o[8];
    if (b < 2048) {
        const int e0 = (b * 256 + t) * 8;
        const int n = e0 >> 21;
        const int s = (e0 >> 10) & 2047;
        const int dm = e0 & 1023, h = dm >> 6, d0 = dm & 63;
        const float4 x0 = *(const float4*)(kg + e0);
        const float4 x1 = *(const float4*)(kg + e0 + 4);
        o[0]=f2bf(x0.x); o[1]=f2bf(x0.y); o[2]=f2bf(x0.z); o[3]=f2bf(x0.w);
        o[4]=f2bf(x1.x); o[5]=f2bf(x1.y); o[6]=f2bf(x1.z); o[7]=f2bf(x1.w);
        const int kt = s >> 6, st = (s >> 4) & 3, m = s & 15;
        const int f = d0 >> 5, qd = (d0 >> 3) & 3;
        u16* dst = kb + ((size_t)((n * 16 + h) * 32 + kt)) * 4096
                      + (st * 2 + f) * 512 + (m + 16 * qd) * 8;
        *(bf16x8*)dst = *(bf16x8*)o;
    } else if (b < 2560) {
        const int e0 = ((b - 2048) * 256 + t) * 8;
        const int col = e0 >> 10, k0 = e0 & 1023;
        const float4 x0 = *(const float4*)(wg + e0);
        const float4 x1 = *(const float4*)(wg + e0 + 4);
        o[0]=f2bf(x0.x); o[1]=f2bf(x0.y); o[2]=f2bf(x0.z); o[3]=f2bf(x0.w);
        o[4]=f2bf(x1.x); o[5]=f2bf(x1.y); o[6]=f2bf(x1.z); o[7]=f2bf(x1.w);
        const int cb = col >> 6, cj = (col >> 4) & 3, m = col & 15;
        const int kt = k0 >> 6, f = (k0 >> 5) & 1, qd = (k0 >> 3) & 3;
        u16* dst = wb + ((size_t)((cb * 16 + kt) * 8 + cj * 2 + f)) * 512
                      + (m + 16 * qd) * 8;
        *(bf16x8*)dst = *(bf16x8*)o;
    } else if (b < 3584) {
        const int bb = b - 2560;
        const int kt = bb & 31, h = (bb >> 5) & 15, n = bb >> 9;
        {
            const int s = t >> 2, d0 = (t & 3) * 16;
            const float* src = vg + ((size_t)(n * SEQL + kt * 64 + s) * DMODEL) + h * 64 + d0;
            u16 w16[16];
            #pragma unroll
            for (int j = 0; j < 16; ++j) w16[j] = f2bf(src[j]);
            *(bf16x8*)&T[s * TSTR + d0]     = *(bf16x8*)&w16[0];
            *(bf16x8*)&T[s * TSTR + d0 + 8] = *(bf16x8*)&w16[8];
        }
        __syncthreads();
        {
            const int d = t >> 2, k0 = (t & 3) * 16;
            u16 w16[16];
            #pragma unroll
            for (int j = 0; j < 16; ++j) w16[j] = T[(k0 + j) * TSTR + d];
            const int t4 = d >> 4, dr = d & 15;
            u16* base = vtb + ((size_t)((n * 16 + h) * 32 + kt)) * 4096;
            #pragma unroll
            for (int g = 0; g < 2; ++g) {
                const int key0 = k0 + g * 8;
                const int kk = key0 >> 5, qk = (key0 >> 3) & 3;
                *(bf16x8*)(base + (t4 * 2 + kk) * 512 + (dr + 16 * qk) * 8)
                    = *(bf16x8*)&w16[g * 8];
            }
        }
    } else {
        #pragma unroll
        for (int i = 0; i < 16; ++i) {
            const int idx = t * 16 + i;
            maskf[idx] = mg[idx] ? 0.0f : -1.0e5f;
        }
    }
}

// ---------- attention: R3 structure (best measured) + XCD swizzle -----------
// 8 waves: waves 0-3 process kt 0..15, waves 4-7 process kt 16..31, each half
// with its own single-buffered K/V LDS region (2-barrier loop). XCD swizzle
// makes the staged K/V reads L2-resident (R4-validated mechanism).
// Final combine via LDS; normalized frag-ordered X written directly.
__global__ __launch_bounds__(512) void attn_fused(
    const float* __restrict__ qg, const u16* __restrict__ kb,
    const u16* __restrict__ vtb, const float* __restrict__ maskf,
    u16* __restrict__ xb)
{
    // K [2 halves][4096] | V [2][4096] | P [8 waves][2048]  = 64 KB
    __shared__ __align__(16) u16 SM[32768];

    // bijective XCD swizzle: each XCD owns 4 (h,n) groups x their 16 qblks,
    // so its K/V working set is 4 x 512 KB = 2 MB < 4 MB L2.
    const int b = blockIdx.x;              // 512 blocks
    const int xcd = b & 7;
    const int j = b >> 3;                  // 0..63
    const int qblk = j & 15;
    const int hn = xcd * 4 + (j >> 4);     // 0..31
    const int h = hn & 15;
    const int n = hn >> 4;

    const int tid = threadIdx.x;
    const int wave = tid >> 6, lane = tid & 63;
    const int half = wave >> 2, w4 = wave & 3;
    const int tloc = tid & 255;            // thread id within half
    const int lrow = lane & 15, quad = lane >> 4;
    const int q0 = qblk * 128;

    u16* const K_lds = SM + half * 4096;
    u16* const V_lds = SM + 8192 + half * 4096;
    u16* const P_lds = SM + 16384 + wave * 2048;

    const u16* ksrc = kb  + ((size_t)(n * 16 + h)) * 131072 + (size_t)half * 65536;
    const u16* vsrc = vtb + ((size_t)(n * 16 + h)) * 131072 + (size_t)half * 65536;
    const float* mrow = maskf + n * SEQL + half * 1024;

    // Q fragments ([q=lane&15][d=quad*8+j]); 2 q-tiles per wave
    bf16x8 qf[2][2];
    #pragma unroll
    for (int qi = 0; qi < 2; ++qi) {
        const float* qp = qg + ((size_t)(n * SEQL + q0 + w4 * 32 + qi * 16 + lrow) * DMODEL) + h * 64 + quad * 8;
        #pragma unroll
        for (int f = 0; f < 2; ++f) {
            const float4 a = *(const float4*)(qp + f * 32);
            const float4 c = *(const float4*)(qp + f * 32 + 4);
            u16* dst = (u16*)&qf[qi][f];
            dst[0]=f2bf(a.x); dst[1]=f2bf(a.y); dst[2]=f2bf(a.z); dst[3]=f2bf(a.w);
            dst[4]=f2bf(c.x); dst[5]=f2bf(c.y); dst[6]=f2bf(c.z); dst[7]=f2bf(c.w);
        }
    }

    bf16x8 onesf;
    #pragma unroll
    for (int jj = 0; jj < 8; ++jj) ((u16*)&onesf)[jj] = 0x3F80;

    f32x4 oacc[2][4];
    f32x4 lacc[2];
    #pragma unroll
    for (int qi = 0; qi < 2; ++qi) {
        lacc[qi] = (f32x4){0.f, 0.f, 0.f, 0.f};
        #pragma unroll
        for (int t4 = 0; t4 < 4; ++t4) oacc[qi][t4] = (f32x4){0.f, 0.f, 0.f, 0.f};
    }

    for (int i = 0; i < 16; ++i) {
        __syncthreads();
        {
            const u16* ks = ksrc + (size_t)i * 4096;
            const u16* vs = vsrc + (size_t)i * 4096;
            #pragma unroll
            for (int c = 0; c < 2; ++c) {
                const int ch = tloc + c * 256;     // 512 chunks of 16B per half
                async16(&K_lds[ch * 8], ks + ch * 8);
                async16(&V_lds[ch * 8], vs + ch * 8);
            }
        }
        __syncthreads();

        // S^T = K Q^T : C col = q (lane&15), C rows = key (quad*4+r)
        #pragma unroll
        for (int st = 0; st < 4; ++st) {
            const bf16x8 kf0 = *(const bf16x8*)&K_lds[(st * 2 + 0) * 512 + lane * 8];
            const bf16x8 kf1 = *(const bf16x8*)&K_lds[(st * 2 + 1) * 512 + lane * 8];
            const f32x4 mv = *(const f32x4*)&mrow[i * 64 + st * 16 + quad * 4];
            // P-write frag coords for key = st*16 + quad*4 + r
            const int kk = st >> 1;
            const int qk = (st & 1) * 2 + (quad >> 1);
            const int j0 = (quad & 1) * 4;
            #pragma unroll
            for (int qi = 0; qi < 2; ++qi) {
                f32x4 sa = (f32x4){0.f, 0.f, 0.f, 0.f};
                sa = __builtin_amdgcn_mfma_f32_16x16x32_bf16(kf0, qf[qi][0], sa, 0, 0, 0);
                sa = __builtin_amdgcn_mfma_f32_16x16x32_bf16(kf1, qf[qi][1], sa, 0, 0, 0);
                float e0v = fexp2(fmaf(sa[0], SCALE2, mv[0]));
                float e1v = fexp2(fmaf(sa[1], SCALE2, mv[1]));
                float e2v = fexp2(fmaf(sa[2], SCALE2, mv[2]));
                float e3v = fexp2(fmaf(sa[3], SCALE2, mv[3]));
                __hip_bfloat162 h0 = __float22bfloat162_rn(make_float2(e0v, e1v));
                __hip_bfloat162 h1 = __float22bfloat162_rn(make_float2(e2v, e3v));
                union { unsigned u[2]; bf16x4 v; } pk;
                pk.u[0] = *(unsigned*)&h0;
                pk.u[1] = *(unsigned*)&h1;
                *(bf16x4*)&P_lds[(qi * 2 + kk) * 512 + (lrow + 16 * qk) * 8 + j0] = pk.v;
            }
        }
        asm volatile("s_waitcnt lgkmcnt(0)" ::: "memory");

        bf16x8 vf[4][2];
        #pragma unroll
        for (int t4 = 0; t4 < 4; ++t4) {
            vf[t4][0] = *(const bf16x8*)&V_lds[(t4 * 2 + 0) * 512 + lane * 8];
            vf[t4][1] = *(const bf16x8*)&V_lds[(t4 * 2 + 1) * 512 + lane * 8];
        }
        #pragma unroll
        for (int qi = 0; qi < 2; ++qi) {
            const bf16x8 pf0 = *(const bf16x8*)&P_lds[(qi * 2 + 0) * 512 + lane * 8];
            const bf16x8 pf1 = *(const bf16x8*)&P_lds[(qi * 2 + 1) * 512 + lane * 8];
            lacc[qi] = __builtin_amdgcn_mfma_f32_16x16x32_bf16(pf0, onesf, lacc[qi], 0, 0, 0);
            lacc[qi] = __builtin_amdgcn_mfma_f32_16x16x32_bf16(pf1, onesf, lacc[qi], 0, 0, 0);
            #pragma unroll
            for (int t4 = 0; t4 < 4; ++t4) {
                oacc[qi][t4] = __builtin_amdgcn_mfma_f32_16x16x32_bf16(pf0, vf[t4][0], oacc[qi][t4], 0, 0, 0);
                oacc[qi][t4] = __builtin_amdgcn_mfma_f32_16x16x32_bf16(pf1, vf[t4][1], oacc[qi][t4], 0, 0, 0);
            }
        }
    }

    // ---- in-block split-K combine ----
    __syncthreads();   // all waves done with K/V/P LDS
    float* const Pf = (float*)(SM + 16384);   // 8192 f32 (32 KB) partial oacc
    float* const Lf = (float*)SM;             // 2048 f32 (8 KB)  partial lacc
    if (half) {
        float* dst = Pf + (size_t)(w4 * 64 + lane) * 32;
        float* ld  = Lf + (size_t)(w4 * 64 + lane) * 8;
        #pragma unroll
        for (int qi = 0; qi < 2; ++qi) {
            *(f32x4*)(ld + qi * 4) = lacc[qi];
            #pragma unroll
            for (int t4 = 0; t4 < 4; ++t4)
                *(f32x4*)(dst + qi * 16 + t4 * 4) = oacc[qi][t4];
        }
    }
    __syncthreads();
    if (!half) {
        const float* src = Pf + (size_t)(w4 * 64 + lane) * 32;
        const float* ls  = Lf + (size_t)(w4 * 64 + lane) * 8;
        #pragma unroll
        for (int qi = 0; qi < 2; ++qi) {
            lacc[qi] += *(const f32x4*)(ls + qi * 4);
            #pragma unroll
            for (int t4 = 0; t4 < 4; ++t4)
                oacc[qi][t4] += *(const f32x4*)(src + qi * 16 + t4 * 4);
        }
        // normalize + write frag-ordered bf16 X (verified mapping)
        #pragma unroll
        for (int qi = 0; qi < 2; ++qi)
            #pragma unroll
            for (int r = 0; r < 4; ++r) {
                const float rinv = 1.0f / lacc[qi][r];
                const int row = n * SEQL + q0 + w4 * 32 + qi * 16 + quad * 4 + r;
                const int rb = row >> 7, rt = (row >> 4) & 7, m = row & 15;
                #pragma unroll
                for (int t4 = 0; t4 < 4; ++t4) {
                    const int f = t4 >> 1;
                    const int qd = (t4 & 1) * 2 + (lrow >> 3);
                    xb[((size_t)((rb * 16 + h) * 16 + rt * 2 + f)) * 512
                       + (m + 16 * qd) * 8 + (lrow & 7)] = f2bf(oacc[qi][t4][r] * rinv);
                }
            }
    }
}

// ---------- FC: out = X @ W^T + b, 128x64 tile, BK=64, frag-ordered ----------
// 2-phase pipelined: double-buffered X/W, prefetch issued before compute.
__global__ __launch_bounds__(256) void fc_kernel(
    const u16* __restrict__ xb, const u16* __restrict__ wb,
    const float* __restrict__ bias, float* __restrict__ out)
{
    // X dbuf 2x8192 | W dbuf 2x4096 (48 KB)
    __shared__ __align__(16) u16 SM[24576];
    u16* const X_lds = SM;            // [2][8192]
    u16* const W_lds = SM + 16384;    // [2][4096]

    const int blk = blockIdx.x;          // 32 rowblocks x 16 colblocks = 512
    const int cb = blk & 15, rb = blk >> 4;
    const int tid = threadIdx.x;
    const int wave = tid >> 6, lane = tid & 63;
    const int lrow = lane & 15, quad = lane >> 4;

    const u16* xs0 = xb + ((size_t)rb * 16) * 8192;
    const u16* ws0 = wb + ((size_t)cb * 16) * 4096;

    f32x4 acc[2][4];
    #pragma unroll
    for (int ri = 0; ri < 2; ++ri)
        #pragma unroll
        for (int cj = 0; cj < 4; ++cj) acc[ri][cj] = (f32x4){0.f, 0.f, 0.f, 0.f};

    {
        #pragma unroll
        for (int i = 0; i < 4; ++i) {
            const int ch = tid + i * 256;          // 1024 chunks
            async16(&X_lds[ch * 8], xs0 + ch * 8);
        }
        #pragma unroll
        for (int i = 0; i < 2; ++i) {
            const int ch = tid + i * 256;          // 512 chunks
            async16(&W_lds[ch * 8], ws0 + ch * 8);
        }
    }
    __syncthreads();

    for (int kt = 0; kt < 16; ++kt) {
        const int cur = kt & 1;
        const u16* const Xc = X_lds + cur * 8192;
        const u16* const Wc = W_lds + cur * 4096;

        if (kt + 1 < 16) {
            const int nxt = cur ^ 1;
            const u16* xs = xs0 + (size_t)(kt + 1) * 8192;
            const u16* ws = ws0 + (size_t)(kt + 1) * 4096;
            #pragma unroll
            for (int i = 0; i < 4; ++i) {
                const int ch = tid + i * 256;
                async16(&X_lds[nxt * 8192 + ch * 8], xs + ch * 8);
            }
            #pragma unroll
            for (int i = 0; i < 2; ++i) {
                const int ch = tid + i * 256;
                async16(&W_lds[nxt * 4096 + ch * 8], ws + ch * 8);
            }
        }

        bf16x8 af[2][2];
        #pragma unroll
        for (int ri = 0; ri < 2; ++ri) {
            af[ri][0] = *(const bf16x8*)&Xc[((wave * 2 + ri) * 2 + 0) * 512 + lane * 8];
            af[ri][1] = *(const bf16x8*)&Xc[((wave * 2 + ri) * 2 + 1) * 512 + lane * 8];
        }
        #pragma unroll
        for (int cj = 0; cj < 4; ++cj) {
            const bf16x8 bf0 = *(const bf16x8*)&Wc[(cj * 2 + 0) * 512 + lane * 8];
            const bf16x8 bf1 = *(const bf16x8*)&Wc[(cj * 2 + 1) * 512 + lane * 8];
            #pragma unroll
            for (int ri = 0; ri < 2; ++ri) {
                acc[ri][cj] = __builtin_amdgcn_mfma_f32_16x16x32_bf16(af[ri][0], bf0, acc[ri][cj], 0, 0, 0);
                acc[ri][cj] = __builtin_amdgcn_mfma_f32_16x16x32_bf16(af[ri][1], bf1, acc[ri][cj], 0, 0, 0);
            }
        }

        __syncthreads();
    }

    const int row0 = rb * 128, col0 = cb * 64;
    #pragma unroll
    for (int ri = 0; ri < 2; ++ri)
        #pragma unroll
        for (int cj = 0; cj < 4; ++cj) {
            const int col = col0 + cj * 16 + lrow;
            const float bv = bias[col];
            #pragma unroll
            for (int r = 0; r < 4; ++r)
                out[(size_t)(row0 + wave * 32 + ri * 16 + quad * 4 + r) * DMODEL + col] = acc[ri][cj][r] + bv;
        }
}

extern "C" void kernel_launch(void* const* d_in, const int* in_sizes, int n_in,
                              void* d_out, int out_size, void* d_ws, size_t ws_size,
                              hipStream_t stream) {
    const float* q   = (const float*)d_in[0];
    const float* k   = (const float*)d_in[1];
    const float* v   = (const float*)d_in[2];
    const int*   m   = (const int*)d_in[3];
    const float* fcw = (const float*)d_in[4];
    const float* fcb = (const float*)d_in[5];
    float* out = (float*)d_out;

    char* ws = (char*)d_ws;
    u16*   kbuf  = (u16*)(ws);                     // 8 MB  frag-ordered K
    u16*   vtbuf = (u16*)(ws + (8u  << 20));       // 8 MB  frag-ordered V^T
    u16*   wbuf  = (u16*)(ws + (16u << 20));       // 2 MB  frag-ordered W
    u16*   xbuf  = (u16*)(ws + (18u << 20));       // 8 MB  frag-ordered X
    float* maskf = (float*)(ws + (26u << 20));     // 16 KB float bias [2][2048]

    pack_all<<<dim3(3585), dim3(256), 0, stream>>>(k, fcw, v, m, kbuf, wbuf, vtbuf, maskf);
    attn_fused<<<dim3(512), dim3(512), 0, stream>>>(q, kbuf, vtbuf, maskf, xbuf);
    fc_kernel<<<dim3(512), dim3(256), 0, stream>>>(xbuf, wbuf, fcb, out);
}